// Round 8
// baseline (280.748 us; speedup 1.0000x reference)
//
#include <hip/hip_runtime.h>
#include <hip/hip_bf16.h>

// Problem: B=4, L=2048, C=1024, H=16, D=64, M=B*L=8192. I/O f32.
// Internal: bf16 MFMA, f32 accumulate. Verified absmax 9.8e-4 (thr 4.04e-3).
// R17: QKV GEMM rebuilt as 256x128-tile (wave = 64Mx128N, acc[2][4]).
//   R16 post-mortem: 1-barrier dbuf-prefetch REINTRODUCED bank conflicts
//   (6.3e6) — gload_lds writes to buf[nxt] run concurrently with ds_reads
//   of buf[cur] on the same LDS pipe. R15's 2-barrier phase separation was
//   the conflict-free config (total 274.95). Invariant 81us across three
//   K-loop variants = LDS-pipe-bound at 1:1 MFMA:read ratio. Fix (R14's
//   attn lever): bigger per-wave tile -> 16 MFMA : 12 reads (1.33x), LDS
//   cy/work -25%, compute phase 2x (hides barrier drain better).
//   2-barrier + both-sides slot-XOR swizzle kept. KNORM fused in epilogue
//   (wave spans exactly 2 heads). Proj GEMM = exact R15 kernel.
//   Attn/prep unchanged from R16.

typedef __attribute__((ext_vector_type(8))) short bf16x8;
typedef __attribute__((ext_vector_type(16))) float f32x16;

#define MAXLOG 4.60517018598809f   // ln(100)
#define LOG2E  1.4426950408889634f

__device__ __forceinline__ float bf2f(unsigned short u) {
    union { unsigned int i; float f; } v; v.i = ((unsigned int)u) << 16; return v.f;
}
__device__ __forceinline__ unsigned short f2bf(float f) {
    union { float f; unsigned int i; } v; v.f = f;
    unsigned int x = v.i;
    return (unsigned short)((x + 0x7FFFu + ((x >> 16) & 1u)) >> 16);  // RNE
}
__device__ __forceinline__ unsigned fbits(float f) {
    union { float f; unsigned u; } v; v.f = f; return v.u;
}
__device__ __forceinline__ bf16x8 pack8(const float* __restrict__ p) {
    float4 a = *(const float4*)p;
    float4 b = *(const float4*)(p + 4);
    bf16x8 r;
    r[0] = (short)f2bf(a.x); r[1] = (short)f2bf(a.y);
    r[2] = (short)f2bf(a.z); r[3] = (short)f2bf(a.w);
    r[4] = (short)f2bf(b.x); r[5] = (short)f2bf(b.y);
    r[6] = (short)f2bf(b.z); r[7] = (short)f2bf(b.w);
    return r;
}
__device__ __forceinline__ void gload_lds16(const void* g, void* l) {
    __builtin_amdgcn_global_load_lds((const __attribute__((address_space(1))) void*)g,
                                     (__attribute__((address_space(3))) void*)l, 16, 0, 0);
}

// ---------------------------------------- fused prep: casts + bias (1 kernel)
__global__ __launch_bounds__(256) void k_prep(
    const float* __restrict__ x, const float* __restrict__ Wqkv,
    const float* __restrict__ Wp, const float* __restrict__ qbia,
    const float* __restrict__ vbia,
    unsigned short* __restrict__ xb, unsigned short* __restrict__ Wqkvb,
    unsigned short* __restrict__ Wpb, float* __restrict__ bias3)
{
    int i = blockIdx.x * 256 + threadIdx.x;
    if (i < 1048576) {
        *(bf16x8*)&xb[(long)i * 8] = pack8(&x[(long)i * 8]);
    } else if (i < 1441792) {
        int j = i - 1048576;
        *(bf16x8*)&Wqkvb[(long)j * 8] = pack8(&Wqkv[(long)j * 8]);
    } else if (i < 1572864) {
        int j = i - 1441792;
        *(bf16x8*)&Wpb[(long)j * 8] = pack8(&Wp[(long)j * 8]);
    } else if (i < 1573248) {
        int j = (i - 1572864) * 8;
        for (int u = 0; u < 8; ++u) {
            int n = j + u;
            float v = 0.0f;
            if (n < 1024) v = qbia[n];
            else if (n >= 2048) v = vbia[n - 2048];
            bias3[n] = v;
        }
    }
}

// ------------------- QKV GEMM: 256x128 tile, wave = 64Mx128N, bf16 out
// 2-barrier phases (write-phase and read-phase disjoint -> conflict-free
// with the slot-XOR swizzle on both sides). KNORM: cols [1024,2048) get
// per-head (64-col) L2 row-normalization fused into the epilogue.
template<bool KNORM>
__global__ __launch_bounds__(256, 2) void k_gemm256(
    const unsigned short* __restrict__ A, const unsigned short* __restrict__ Bh,
    const float* __restrict__ bias, unsigned short* __restrict__ Cp,
    int N, int K)
{
    __shared__ unsigned short As[256 * 32];   // 16KB
    __shared__ unsigned short Bs[128 * 32];   // 8KB
    const int t = threadIdx.x, wave = t >> 6, lane = t & 63;
    const int m32 = lane & 31, half = lane >> 5;
    const int bm = blockIdx.x * 256, bn = blockIdx.y * 128;
    f32x16 acc[2][4] = {};

    const int srow = lane >> 2;        // 0..15
    // write-side swizzle: slot = (lane&3) ^ ((srow>>1)&3)
    const int scol = (((lane & 3) ^ ((lane >> 3) & 3))) * 8;
    // wave stages A-chunks [wave*4, wave*4+4) and B-chunks [wave*2, wave*2+2)
    long gA[4], gB[2];
    for (int i = 0; i < 4; ++i)
        gA[i] = (long)(bm + (wave * 4 + i) * 16 + srow) * K + scol;
    for (int i = 0; i < 2; ++i)
        gB[i] = (long)(bn + (wave * 2 + i) * 16 + srow) * K + scol;

    // read-side swizzle term for this lane's fragment rows
    const int swz = (m32 >> 1) & 3;

    for (int kt = 0; kt < K; kt += 32) {
        __syncthreads();
        for (int i = 0; i < 4; ++i)
            gload_lds16(&A[gA[i] + kt], &As[(wave * 4 + i) * 512]);
        for (int i = 0; i < 2; ++i)
            gload_lds16(&Bh[gB[i] + kt], &Bs[(wave * 2 + i) * 512]);
        __syncthreads();
        bf16x8 af[2][2], bfr[4][2];
        for (int mt = 0; mt < 2; ++mt)
            for (int f = 0; f < 2; ++f)
                af[mt][f] = *(const bf16x8*)&As[(wave * 64 + mt * 32 + m32) * 32 +
                                                (((f * 2 + half) ^ swz) * 8)];
        for (int nt = 0; nt < 4; ++nt)
            for (int f = 0; f < 2; ++f)
                bfr[nt][f] = *(const bf16x8*)&Bs[(nt * 32 + m32) * 32 +
                                                 (((f * 2 + half) ^ swz) * 8)];
        for (int f = 0; f < 2; ++f)
            for (int mt = 0; mt < 2; ++mt)
                for (int nt = 0; nt < 4; ++nt)
                    acc[mt][nt] = __builtin_amdgcn_mfma_f32_32x32x16_bf16(
                        af[mt][f], bfr[nt][f], acc[mt][nt], 0, 0, 0);
    }

    // epilogue: 32x32 C/D layout col=lane&31, row=(r&3)+8*(r>>2)+4*half.
    // Wave spans 128 cols = 2 heads: nt{0,1}=head A, nt{2,3}=head B.
    // Halves hold DIFFERENT rows -> shfl_xor masks <=16 reduce per-row.
    const bool isk = KNORM && (bn >= 1024) && (bn < 2048);
    float bv[4];
    for (int nt = 0; nt < 4; ++nt) bv[nt] = bias[bn + nt * 32 + m32];
    for (int mt = 0; mt < 2; ++mt)
        for (int r = 0; r < 16; ++r) {
            int gm = bm + wave * 64 + mt * 32 + (r & 3) + 8 * (r >> 2) + 4 * half;
            float v0 = acc[mt][0][r] + bv[0];
            float v1 = acc[mt][1][r] + bv[1];
            float v2 = acc[mt][2][r] + bv[2];
            float v3 = acc[mt][3][r] + bv[3];
            if (isk) {
                float sa = v0 * v0 + v1 * v1;
                sa += __shfl_xor(sa, 1, 64);
                sa += __shfl_xor(sa, 2, 64);
                sa += __shfl_xor(sa, 4, 64);
                sa += __shfl_xor(sa, 8, 64);
                sa += __shfl_xor(sa, 16, 64);
                float sb = v2 * v2 + v3 * v3;
                sb += __shfl_xor(sb, 1, 64);
                sb += __shfl_xor(sb, 2, 64);
                sb += __shfl_xor(sb, 4, 64);
                sb += __shfl_xor(sb, 8, 64);
                sb += __shfl_xor(sb, 16, 64);
                float ia = 1.0f / fmaxf(sqrtf(sa), 1e-12f);
                float ib = 1.0f / fmaxf(sqrtf(sb), 1e-12f);
                v0 *= ia; v1 *= ia; v2 *= ib; v3 *= ib;
            }
            long rowb = (long)gm * N + bn + m32;
            Cp[rowb]      = f2bf(v0);
            Cp[rowb + 32] = f2bf(v1);
            Cp[rowb + 64] = f2bf(v2);
            Cp[rowb + 96] = f2bf(v3);
        }
}

// ------------------- proj GEMM: exact R15 kernel (single-buf, 2-barrier,
// slot-XOR swizzle both sides) — the conflict-free 274.95us config.
template<bool OUT_F32>
__global__ __launch_bounds__(256) void k_gemm_lds(
    const unsigned short* __restrict__ A, const unsigned short* __restrict__ Bh,
    const float* __restrict__ bias, void* __restrict__ Cp, int N, int K)
{
    __shared__ unsigned short As[128 * 32];
    __shared__ unsigned short Bs[128 * 32];
    const int t = threadIdx.x, wave = t >> 6, lane = t & 63;
    const int m32 = lane & 31, half = lane >> 5;
    const int bm = blockIdx.x * 128, bn = blockIdx.y * 128;
    const int wr = (wave >> 1) * 64, wc = (wave & 1) * 64;
    f32x16 acc[2][2] = {};

    const int srow = lane >> 2;        // 0..15
    const int scol = (((lane & 3) ^ ((lane >> 3) & 3))) * 8;
    const int c0 = wave * 2, c1 = wave * 2 + 1;
    const long ga0 = (long)(bm + c0 * 16 + srow) * K + scol;
    const long ga1 = (long)(bm + c1 * 16 + srow) * K + scol;
    const long gb0 = (long)(bn + c0 * 16 + srow) * K + scol;
    const long gb1 = (long)(bn + c1 * 16 + srow) * K + scol;

    const int swz = (m32 >> 1) & 3;

    for (int kt = 0; kt < K; kt += 32) {
        __syncthreads();
        gload_lds16(&A[ga0 + kt], &As[c0 * 512]);
        gload_lds16(&A[ga1 + kt], &As[c1 * 512]);
        gload_lds16(&Bh[gb0 + kt], &Bs[c0 * 512]);
        gload_lds16(&Bh[gb1 + kt], &Bs[c1 * 512]);
        __syncthreads();
        bf16x8 af[2][2], bfr[2][2];
        for (int mt = 0; mt < 2; ++mt)
            for (int f = 0; f < 2; ++f)
                af[mt][f] = *(const bf16x8*)&As[(wr + mt * 32 + m32) * 32 +
                                                (((f * 2 + half) ^ swz) * 8)];
        for (int nt = 0; nt < 2; ++nt)
            for (int f = 0; f < 2; ++f)
                bfr[nt][f] = *(const bf16x8*)&Bs[(wc + nt * 32 + m32) * 32 +
                                                 (((f * 2 + half) ^ swz) * 8)];
        for (int f = 0; f < 2; ++f)
            for (int mt = 0; mt < 2; ++mt)
                for (int nt = 0; nt < 2; ++nt)
                    acc[mt][nt] = __builtin_amdgcn_mfma_f32_32x32x16_bf16(
                        af[mt][f], bfr[nt][f], acc[mt][nt], 0, 0, 0);
    }
    for (int mt = 0; mt < 2; ++mt)
        for (int nt = 0; nt < 2; ++nt) {
            int gn = bn + wc + nt * 32 + m32;
            float bv = bias[gn];
            for (int r = 0; r < 16; ++r) {
                int gm = bm + wr + mt * 32 + (r & 3) + 8 * (r >> 2) + 4 * half;
                float val = acc[mt][nt][r] + bv;
                if (OUT_F32) ((float*)Cp)[(long)gm * N + gn] = val;
                else ((unsigned short*)Cp)[(long)gm * N + gn] = f2bf(val);
            }
        }
}

// ------------------------- v transpose (k-norm fused into QKV GEMM)
__global__ __launch_bounds__(256) void k_prep_v(
    const unsigned short* __restrict__ qkv, unsigned short* __restrict__ vT)
{
    __shared__ unsigned short Vsh[64 * 72];
    const int t = threadIdx.x;
    const int bh = blockIdx.y, l0 = blockIdx.x * 64;
    const int h = bh & 15, b = bh >> 4;
    const int ll = t >> 2, c16 = (t & 3) * 16;
    const long rowbase = (long)(b * 2048 + l0 + ll) * 3072;

    *(bf16x8*)&Vsh[ll * 72 + c16]     = *(const bf16x8*)&qkv[rowbase + 2048 + h * 64 + c16];
    *(bf16x8*)&Vsh[ll * 72 + c16 + 8] = *(const bf16x8*)&qkv[rowbase + 2048 + h * 64 + c16 + 8];
    __syncthreads();
    const int d = t >> 2, ls = (t & 3) * 16;
    unsigned short tmp[16];
    for (int j = 0; j < 16; ++j) tmp[j] = Vsh[(ls + j) * 72 + d];
    long dst = (long)(bh * 64 + d) * 2048 + l0 + ls;
    *(bf16x8*)&vT[dst]     = *(bf16x8*)&tmp[0];
    *(bf16x8*)&vT[dst + 8] = *(bf16x8*)&tmp[8];
}

// ------------------------------------------------------------ flash attention
// 32x32x16 MFMA, S^T form (key-permutation: P stays in registers).
// R14 structure (64 q-rows/wave, two 32-q groups sharing K/V frag regs).
// K staged from the qkv k-plane (normalized in GEMM epilogue).
__global__ __launch_bounds__(256, 2) void k_attn32(
    const unsigned short* __restrict__ qkv,
    const unsigned short* __restrict__ vT, const float* __restrict__ sml,
    unsigned short* __restrict__ attn)
{
    __shared__ unsigned short Ks[2][64 * 72];
    __shared__ unsigned short Vs[2][64 * 72];
    const int t = threadIdx.x, wave = t >> 6, lane = t & 63;
    const int m32 = lane & 31, half = lane >> 5;
    const int wg = blockIdx.x;
    const int logical = (wg & 7) * 64 + (wg >> 3);
    const int bh = logical >> 3, qblk = logical & 7;
    const int h = bh & 15, b = bh >> 4;
    const int q0 = qblk * 256 + wave * 64;     // rows q0..q0+31 (A), q0+32..q0+63 (B)
    const float scale = __expf(fminf(sml[h], MAXLOG));
    const float c2 = scale * LOG2E;   // shift for the (rare) large-scale path

    // permuted physical key row for the S^T A-frag (swap quads 1<->2, 5<->6)
    const int qd = m32 >> 2, lo = qd & 3;
    const int prow = ((((lo == 1) || (lo == 2)) ? (qd ^ 3) : qd) << 2) | (m32 & 3);

    // fused q load + L2-normalize for both q-groups; scale folded with LOG2E
    bf16x8 aqA[4], aqB[4];
    {
        long base = (long)(b * 2048 + q0 + m32) * 3072 + h * 64;
        float e[32]; float ss = 0.f;
        for (int f = 0; f < 4; ++f) {
            aqA[f] = *(const bf16x8*)&qkv[base + f * 16 + half * 8];
            for (int j = 0; j < 8; ++j) { float x = bf2f((unsigned short)aqA[f][j]); e[f * 8 + j] = x; ss += x * x; }
        }
        ss += __shfl_xor(ss, 32, 64);
        float rs = (scale * LOG2E) / fmaxf(sqrtf(ss), 1e-12f);
        for (int f = 0; f < 4; ++f)
            for (int j = 0; j < 8; ++j) aqA[f][j] = (short)f2bf(e[f * 8 + j] * rs);
    }
    {
        long base = (long)(b * 2048 + q0 + 32 + m32) * 3072 + h * 64;
        float e[32]; float ss = 0.f;
        for (int f = 0; f < 4; ++f) {
            aqB[f] = *(const bf16x8*)&qkv[base + f * 16 + half * 8];
            for (int j = 0; j < 8; ++j) { float x = bf2f((unsigned short)aqB[f][j]); e[f * 8 + j] = x; ss += x * x; }
        }
        ss += __shfl_xor(ss, 32, 64);
        float rs = (scale * LOG2E) / fmaxf(sqrtf(ss), 1e-12f);
        for (int f = 0; f < 4; ++f)
            for (int j = 0; j < 8; ++j) aqB[f][j] = (short)f2bf(e[f * 8 + j] * rs);
    }

    f32x16 oA0 = {}, oA1 = {}, lA = {};
    f32x16 oB0 = {}, oB1 = {}, lB = {};
    bf16x8 ones; for (int i = 0; i < 8; ++i) ones[i] = (short)0x3F80;
    const int sr = t >> 2, sc = (t & 3) * 16;
    // K rows live in the qkv k-plane: row l at qkv[(b*2048+l)*3072 + 1024 + h*64]
    const long kqrow = (long)(b * 2048) * 3072 + 1024 + h * 64;
    const long vbase = (long)bh * 64 * 2048;

#define LOADT(kt) \
    kpA = *(const bf16x8*)&qkv[kqrow + (long)((kt) + sr) * 3072 + sc];      \
    kpB = *(const bf16x8*)&qkv[kqrow + (long)((kt) + sr) * 3072 + sc + 8];  \
    vpA = *(const bf16x8*)&vT[vbase + (long)sr * 2048 + (kt) + sc];         \
    vpB = *(const bf16x8*)&vT[vbase + (long)sr * 2048 + (kt) + sc + 8];

#define STORET(buf) \
    *(bf16x8*)&Ks[buf][sr * 72 + sc]     = kpA;  \
    *(bf16x8*)&Ks[buf][sr * 72 + sc + 8] = kpB;  \
    *(bf16x8*)&Vs[buf][sr * 72 + sc]     = vpA;  \
    *(bf16x8*)&Vs[buf][sr * 72 + sc + 8] = vpB;

// QK^T + exp2 + pack for one q-group (AQ) into two packed A-frags (AP0,AP1)
#define SCORE(AQ, AP0, AP1, KF0, KF1, KF2, KF3, SUB) \
    {                                                                                      \
        f32x16 s = {};                                                                     \
        s = __builtin_amdgcn_mfma_f32_32x32x16_bf16(KF0, AQ[0], s, 0, 0, 0);               \
        s = __builtin_amdgcn_mfma_f32_32x32x16_bf16(KF1, AQ[1], s, 0, 0, 0);               \
        s = __builtin_amdgcn_mfma_f32_32x32x16_bf16(KF2, AQ[2], s, 0, 0, 0);               \
        s = __builtin_amdgcn_mfma_f32_32x32x16_bf16(KF3, AQ[3], s, 0, 0, 0);               \
        unsigned pu[16];                                                                   \
        for (int j = 0; j < 16; ++j)                                                       \
            pu[j] = fbits(__builtin_amdgcn_exp2f(s[j] - (SUB)));                           \
        uint4 a0u, a1u;                                                                    \
        a0u.x = __builtin_amdgcn_perm(pu[1],  pu[0],  0x07060302u);                        \
        a0u.y = __builtin_amdgcn_perm(pu[3],  pu[2],  0x07060302u);                        \
        a0u.z = __builtin_amdgcn_perm(pu[5],  pu[4],  0x07060302u);                        \
        a0u.w = __builtin_amdgcn_perm(pu[7],  pu[6],  0x07060302u);                        \
        a1u.x = __builtin_amdgcn_perm(pu[9],  pu[8],  0x07060302u);                        \
        a1u.y = __builtin_amdgcn_perm(pu[11], pu[10], 0x07060302u);                        \
        a1u.z = __builtin_amdgcn_perm(pu[13], pu[12], 0x07060302u);                        \
        a1u.w = __builtin_amdgcn_perm(pu[15], pu[14], 0x07060302u);                        \
        __builtin_memcpy(&AP0, &a0u, 16); __builtin_memcpy(&AP1, &a1u, 16);                \
    }

#define ATTN_STEP(KS, VS, SUB) \
    for (int ktile = 0; ktile < 2; ++ktile) {                                              \
        const unsigned short* krow = &KS[(ktile * 32 + prow) * 72 + half * 8];             \
        bf16x8 kf0 = *(const bf16x8*)&krow[0];                                             \
        bf16x8 kf1 = *(const bf16x8*)&krow[16];                                            \
        bf16x8 kf2 = *(const bf16x8*)&krow[32];                                            \
        bf16x8 kf3 = *(const bf16x8*)&krow[48];                                            \
        bf16x8 apA0, apA1, apB0, apB1;                                                     \
        SCORE(aqA, apA0, apA1, kf0, kf1, kf2, kf3, SUB)                                    \
        SCORE(aqB, apB0, apB1, kf0, kf1, kf2, kf3, SUB)                                    \
        for (int c = 0; c < 2; ++c) {                                                      \
            bf16x8 aA = c ? apA1 : apA0;                                                   \
            bf16x8 aB = c ? apB1 : apB0;                                                   \
            bf16x8 bv0 = *(const bf16x8*)&VS[m32 * 72        + ktile * 32 + c * 16 + half * 8]; \
            bf16x8 bv1 = *(const bf16x8*)&VS[(32 + m32) * 72 + ktile * 32 + c * 16 + half * 8]; \
            oA0 = __builtin_amdgcn_mfma_f32_32x32x16_bf16(aA, bv0, oA0, 0, 0, 0);          \
            oA1 = __builtin_amdgcn_mfma_f32_32x32x16_bf16(aA, bv1, oA1, 0, 0, 0);          \
            lA  = __builtin_amdgcn_mfma_f32_32x32x16_bf16(aA, ones, lA, 0, 0, 0);          \
            oB0 = __builtin_amdgcn_mfma_f32_32x32x16_bf16(aB, bv0, oB0, 0, 0, 0);          \
            oB1 = __builtin_amdgcn_mfma_f32_32x32x16_bf16(aB, bv1, oB1, 0, 0, 0);          \
            lB  = __builtin_amdgcn_mfma_f32_32x32x16_bf16(aB, ones, lB, 0, 0, 0);          \
        }                                                                                  \
    }

#define KLOOP(SUB) \
    for (int kt = 0; kt < 2048; kt += 128) {                 \
        LOADT(kt + 64)                                       \
        ATTN_STEP(Ks[0], Vs[0], SUB)                         \
        STORET(1)                                            \
        __syncthreads();                                     \
        const bool more = (kt + 128) < 2048;                 \
        if (more) { LOADT(kt + 128) }                        \
        ATTN_STEP(Ks[1], Vs[1], SUB)                         \
        if (more) {                                          \
            STORET(0)                                        \
            __syncthreads();                                 \
        }                                                    \
    }

    bf16x8 kpA, kpB, vpA, vpB;
    LOADT(0)
    STORET(0)
    __syncthreads();

    if (c2 < 30.0f) {      // wave-uniform; scale=4 here => fast path
        KLOOP(0.0f)        // s - 0.0f folds away: no per-score VALU shift
    } else {
        KLOOP(c2)          // overflow-safe general path
    }
#undef LOADT
#undef STORET
#undef SCORE
#undef ATTN_STEP
#undef KLOOP

    // epilogue: divide by rowsum (lacc reg r matches o reg r), write attn[B,L,C]
    for (int r = 0; r < 16; ++r) {
        int m = (r & 3) + 8 * (r >> 2) + 4 * half;
        float invA = 1.0f / lA[r];
        long dstA = (long)(b * 2048 + q0 + m) * 1024 + h * 64;
        attn[dstA + m32]      = f2bf(oA0[r] * invA);
        attn[dstA + 32 + m32] = f2bf(oA1[r] * invA);
        float invB = 1.0f / lB[r];
        long dstB = (long)(b * 2048 + q0 + 32 + m) * 1024 + h * 64;
        attn[dstB + m32]      = f2bf(oB0[r] * invB);
        attn[dstB + 32 + m32] = f2bf(oB1[r] * invB);
    }
}

// ---------------------------------------------------------------------------
extern "C" void kernel_launch(void* const* d_in, const int* in_sizes, int n_in,
                              void* d_out, int out_size, void* d_ws, size_t ws_size,
                              hipStream_t stream) {
    const float* x    = (const float*)d_in[0];
    const float* Wqkv = (const float*)d_in[1];
    const float* qbia = (const float*)d_in[2];
    const float* vbia = (const float*)d_in[3];
    const float* sml  = (const float*)d_in[4];
    const float* Wp   = (const float*)d_in[5];
    const float* bp   = (const float*)d_in[6];

    char* ws = (char*)d_ws;
    unsigned short* qkv   = (unsigned short*)ws;                    // [0, 50.33MB)
    unsigned short* Wqkvb = (unsigned short*)(ws + 50331648);       // 6.29MB
    unsigned short* vT    = (unsigned short*)(ws + 67108864);       // hosts xb first
    unsigned short* xb    = vT;
    unsigned short* attnb = (unsigned short*)(ws + 83886080);
    float*          bias3 = (float*)(ws + 100663296);               // 12KB
    unsigned short* Wpb   = (unsigned short*)(ws + 100679680);      // 2MB
    float*          out   = (float*)d_out;

    hipLaunchKernelGGL(k_prep, dim3(6146), dim3(256), 0, stream,
                       x, Wqkv, Wp, qbia, vbia, xb, Wqkvb, Wpb, bias3);
    hipLaunchKernelGGL((k_gemm256<true>), dim3(32, 24), dim3(256), 0, stream,
                       xb, Wqkvb, bias3, qkv, 3072, 1024);
    hipLaunchKernelGGL(k_prep_v, dim3(32, 64), dim3(256), 0, stream, qkv, vT);
    hipLaunchKernelGGL(k_attn32, dim3(512), dim3(256), 0, stream, qkv, vT, sml, attnb);
    hipLaunchKernelGGL((k_gemm_lds<true>), dim3(64, 8), dim3(256), 0, stream,
                       attnb, Wpb, bp, (void*)out, 1024, 1024);
}

// Round 9
// 275.953 us; speedup vs baseline: 1.0174x; 1.0174x over previous
//
#include <hip/hip_runtime.h>
#include <hip/hip_bf16.h>

// Problem: B=4, L=2048, C=1024, H=16, D=64, M=B*L=8192. I/O f32.
// Internal: bf16 MFMA, f32 accumulate. Verified absmax 9.8e-4 (thr 4.04e-3).
// R18: tile-packed GEMM operands. R17 diagnosis: QKV GEMM is bound by
//   L2 staging traffic (786MB at 128^2 tiles, ~23us minimum) delivered as
//   16 scattered 64B segments per gload_lds (half-line waste -> ~2x).
//   Residual bank-conflict counter ~4cy/ds_read_b128 is the intrinsic b128
//   cost (m134), not a real conflict — swizzle already at floor.
//   Fix: k_prep writes xb/Wqkvb/Wpb in 1KB chunk layout (16 rows x 32
//   cols, slot-XOR pre-applied) so every gload_lds is ONE contiguous 1KB
//   burst (8 full 128B lines). LDS content is BIT-IDENTICAL to R15's; only
//   the global source addressing changes. GEMM = R15 config (128^2,
//   2-barrier, single-buf, both-sides swizzle) + R16's verified KNORM
//   epilogue. Proj: packed B (Wpb), unpacked A (attnb). Attn untouched.

typedef __attribute__((ext_vector_type(8))) short bf16x8;
typedef __attribute__((ext_vector_type(16))) float f32x16;

#define MAXLOG 4.60517018598809f   // ln(100)
#define LOG2E  1.4426950408889634f

__device__ __forceinline__ float bf2f(unsigned short u) {
    union { unsigned int i; float f; } v; v.i = ((unsigned int)u) << 16; return v.f;
}
__device__ __forceinline__ unsigned short f2bf(float f) {
    union { float f; unsigned int i; } v; v.f = f;
    unsigned int x = v.i;
    return (unsigned short)((x + 0x7FFFu + ((x >> 16) & 1u)) >> 16);  // RNE
}
__device__ __forceinline__ unsigned fbits(float f) {
    union { float f; unsigned u; } v; v.f = f; return v.u;
}
__device__ __forceinline__ bf16x8 pack8(const float* __restrict__ p) {
    float4 a = *(const float4*)p;
    float4 b = *(const float4*)(p + 4);
    bf16x8 r;
    r[0] = (short)f2bf(a.x); r[1] = (short)f2bf(a.y);
    r[2] = (short)f2bf(a.z); r[3] = (short)f2bf(a.w);
    r[4] = (short)f2bf(b.x); r[5] = (short)f2bf(b.y);
    r[6] = (short)f2bf(b.z); r[7] = (short)f2bf(b.w);
    return r;
}
__device__ __forceinline__ void gload_lds16(const void* g, void* l) {
    __builtin_amdgcn_global_load_lds((const __attribute__((address_space(1))) void*)g,
                                     (__attribute__((address_space(3))) void*)l, 16, 0, 0);
}

// --------------------- fused prep: casts -> tile-packed layout + bias
// Packed layout (per matrix, K=1024, KC=32 chunks of 32 cols):
//   chunk id = row16 * KC + kchunk; chunk = 512 ushorts (1KB).
//   position l*8 (l=0..63) holds source (row rin=l>>2,
//   colquad cq=(l&3)^((rin>>1)&3)) — the slot-XOR swizzle pre-applied,
//   so GEMM's gload_lds reads chunkbase + lane*16B contiguously.
__global__ __launch_bounds__(256) void k_prep(
    const float* __restrict__ x, const float* __restrict__ Wqkv,
    const float* __restrict__ Wp, const float* __restrict__ qbia,
    const float* __restrict__ vbia,
    unsigned short* __restrict__ xb, unsigned short* __restrict__ Wqkvb,
    unsigned short* __restrict__ Wpb, float* __restrict__ bias3)
{
    int i = blockIdx.x * 256 + threadIdx.x;
    if (i < 1048576) {              // xb: M=8192 rows -> 16384 chunks
        int chunk = i >> 6, l = i & 63;
        int r16 = chunk >> 5, kc = chunk & 31;
        int rin = l >> 2, cq = (l & 3) ^ ((rin >> 1) & 3);
        long src = (long)(r16 * 16 + rin) * 1024 + kc * 32 + cq * 8;
        *(bf16x8*)&xb[(long)i * 8] = pack8(&x[src]);
    } else if (i < 1441792) {       // Wqkvb: N=3072 rows -> 6144 chunks
        int j = i - 1048576;
        int chunk = j >> 6, l = j & 63;
        int r16 = chunk >> 5, kc = chunk & 31;
        int rin = l >> 2, cq = (l & 3) ^ ((rin >> 1) & 3);
        long src = (long)(r16 * 16 + rin) * 1024 + kc * 32 + cq * 8;
        *(bf16x8*)&Wqkvb[(long)j * 8] = pack8(&Wqkv[src]);
    } else if (i < 1572864) {       // Wpb: N=1024 rows -> 2048 chunks
        int j = i - 1441792;
        int chunk = j >> 6, l = j & 63;
        int r16 = chunk >> 5, kc = chunk & 31;
        int rin = l >> 2, cq = (l & 3) ^ ((rin >> 1) & 3);
        long src = (long)(r16 * 16 + rin) * 1024 + kc * 32 + cq * 8;
        *(bf16x8*)&Wpb[(long)j * 8] = pack8(&Wp[src]);
    } else if (i < 1573248) {
        int j = (i - 1572864) * 8;
        for (int u = 0; u < 8; ++u) {
            int n = j + u;
            float v = 0.0f;
            if (n < 1024) v = qbia[n];
            else if (n >= 2048) v = vbia[n - 2048];
            bias3[n] = v;
        }
    }
}

// ------------------- GEMM, 128x128 tile, 32x32x16 MFMA, 2-barrier,
// both-sides slot-XOR swizzle (R15 proven config). PA/PB select packed
// (chunk-contiguous) vs row-major scattered staging source. KNORM fuses
// per-head k L2-normalization for cols [1024,2048) (R16-verified).
template<bool OUT_F32, bool KNORM, bool PA, bool PB>
__global__ __launch_bounds__(256) void k_gemm_lds(
    const unsigned short* __restrict__ A, const unsigned short* __restrict__ Bh,
    const float* __restrict__ bias, void* __restrict__ Cp, int N, int K)
{
    __shared__ unsigned short As[128 * 32];
    __shared__ unsigned short Bs[128 * 32];
    const int t = threadIdx.x, wave = t >> 6, lane = t & 63;
    const int m32 = lane & 31, half = lane >> 5;
    const int bm = blockIdx.x * 128, bn = blockIdx.y * 128;
    const int wr = (wave >> 1) * 64, wc = (wave & 1) * 64;
    f32x16 acc[2][2] = {};

    const int KC = K >> 5;
    const int srow = lane >> 2;
    const int scol = (((lane & 3) ^ ((lane >> 3) & 3))) * 8;
    const int c0 = wave * 2, c1 = wave * 2 + 1;
    // staging source bases: packed = chunk-contiguous, unpacked = scattered
    long a0, a1, b0, b1;
    if (PA) { a0 = (long)((bm >> 4) + c0) * KC * 512 + lane * 8;
              a1 = (long)((bm >> 4) + c1) * KC * 512 + lane * 8; }
    else    { a0 = (long)(bm + c0 * 16 + srow) * K + scol;
              a1 = (long)(bm + c1 * 16 + srow) * K + scol; }
    if (PB) { b0 = (long)((bn >> 4) + c0) * KC * 512 + lane * 8;
              b1 = (long)((bn >> 4) + c1) * KC * 512 + lane * 8; }
    else    { b0 = (long)(bn + c0 * 16 + srow) * K + scol;
              b1 = (long)(bn + c1 * 16 + srow) * K + scol; }

    const int swz = (m32 >> 1) & 3;

    for (int kt = 0; kt < K; kt += 32) {
        __syncthreads();
        // packed step stride: (kt>>5)*512 ushorts = kt*16
        gload_lds16(&A[a0 + (PA ? kt * 16 : kt)], &As[c0 * 512]);
        gload_lds16(&A[a1 + (PA ? kt * 16 : kt)], &As[c1 * 512]);
        gload_lds16(&Bh[b0 + (PB ? kt * 16 : kt)], &Bs[c0 * 512]);
        gload_lds16(&Bh[b1 + (PB ? kt * 16 : kt)], &Bs[c1 * 512]);
        __syncthreads();
        bf16x8 af[2][2], bfr[2][2];
        for (int mt = 0; mt < 2; ++mt)
            for (int f = 0; f < 2; ++f)
                af[mt][f] = *(const bf16x8*)&As[(wr + mt * 32 + m32) * 32 +
                                                (((f * 2 + half) ^ swz) * 8)];
        for (int nt = 0; nt < 2; ++nt)
            for (int f = 0; f < 2; ++f)
                bfr[nt][f] = *(const bf16x8*)&Bs[(wc + nt * 32 + m32) * 32 +
                                                 (((f * 2 + half) ^ swz) * 8)];
        for (int f = 0; f < 2; ++f)
            for (int mt = 0; mt < 2; ++mt)
                for (int nt = 0; nt < 2; ++nt)
                    acc[mt][nt] = __builtin_amdgcn_mfma_f32_32x32x16_bf16(
                        af[mt][f], bfr[nt][f], acc[mt][nt], 0, 0, 0);
    }

    // epilogue: 32x32 C/D layout col=lane&31, row=(r&3)+8*(r>>2)+4*half.
    // KNORM: wave's wc-span = one head's 64 cols; halves hold DIFFERENT
    // rows -> shfl_xor masks <=16 reduce each half separately.
    const bool isk = KNORM && (bn >= 1024) && (bn < 2048);
    const float bv0 = bias[bn + wc + m32];
    const float bv1 = bias[bn + wc + 32 + m32];
    for (int mt = 0; mt < 2; ++mt)
        for (int r = 0; r < 16; ++r) {
            int gm = bm + wr + mt * 32 + (r & 3) + 8 * (r >> 2) + 4 * half;
            float v0 = acc[mt][0][r] + bv0;
            float v1 = acc[mt][1][r] + bv1;
            if (isk) {
                float ss = v0 * v0 + v1 * v1;
                ss += __shfl_xor(ss, 1, 64);
                ss += __shfl_xor(ss, 2, 64);
                ss += __shfl_xor(ss, 4, 64);
                ss += __shfl_xor(ss, 8, 64);
                ss += __shfl_xor(ss, 16, 64);
                float inv = 1.0f / fmaxf(sqrtf(ss), 1e-12f);
                v0 *= inv; v1 *= inv;
            }
            if (OUT_F32) {
                ((float*)Cp)[(long)gm * N + bn + wc + m32]      = v0;
                ((float*)Cp)[(long)gm * N + bn + wc + 32 + m32] = v1;
            } else {
                ((unsigned short*)Cp)[(long)gm * N + bn + wc + m32]      = f2bf(v0);
                ((unsigned short*)Cp)[(long)gm * N + bn + wc + 32 + m32] = f2bf(v1);
            }
        }
}

// ------------------------- v transpose (k-norm fused into QKV GEMM)
__global__ __launch_bounds__(256) void k_prep_v(
    const unsigned short* __restrict__ qkv, unsigned short* __restrict__ vT)
{
    __shared__ unsigned short Vsh[64 * 72];
    const int t = threadIdx.x;
    const int bh = blockIdx.y, l0 = blockIdx.x * 64;
    const int h = bh & 15, b = bh >> 4;
    const int ll = t >> 2, c16 = (t & 3) * 16;
    const long rowbase = (long)(b * 2048 + l0 + ll) * 3072;

    *(bf16x8*)&Vsh[ll * 72 + c16]     = *(const bf16x8*)&qkv[rowbase + 2048 + h * 64 + c16];
    *(bf16x8*)&Vsh[ll * 72 + c16 + 8] = *(const bf16x8*)&qkv[rowbase + 2048 + h * 64 + c16 + 8];
    __syncthreads();
    const int d = t >> 2, ls = (t & 3) * 16;
    unsigned short tmp[16];
    for (int j = 0; j < 16; ++j) tmp[j] = Vsh[(ls + j) * 72 + d];
    long dst = (long)(bh * 64 + d) * 2048 + l0 + ls;
    *(bf16x8*)&vT[dst]     = *(bf16x8*)&tmp[0];
    *(bf16x8*)&vT[dst + 8] = *(bf16x8*)&tmp[8];
}

// ------------------------------------------------------------ flash attention
// 32x32x16 MFMA, S^T form (key-permutation: P stays in registers).
// R14 structure (64 q-rows/wave, two 32-q groups sharing K/V frag regs).
// K staged from the qkv k-plane (normalized in GEMM epilogue).
__global__ __launch_bounds__(256, 2) void k_attn32(
    const unsigned short* __restrict__ qkv,
    const unsigned short* __restrict__ vT, const float* __restrict__ sml,
    unsigned short* __restrict__ attn)
{
    __shared__ unsigned short Ks[2][64 * 72];
    __shared__ unsigned short Vs[2][64 * 72];
    const int t = threadIdx.x, wave = t >> 6, lane = t & 63;
    const int m32 = lane & 31, half = lane >> 5;
    const int wg = blockIdx.x;
    const int logical = (wg & 7) * 64 + (wg >> 3);
    const int bh = logical >> 3, qblk = logical & 7;
    const int h = bh & 15, b = bh >> 4;
    const int q0 = qblk * 256 + wave * 64;     // rows q0..q0+31 (A), q0+32..q0+63 (B)
    const float scale = __expf(fminf(sml[h], MAXLOG));
    const float c2 = scale * LOG2E;   // shift for the (rare) large-scale path

    // permuted physical key row for the S^T A-frag (swap quads 1<->2, 5<->6)
    const int qd = m32 >> 2, lo = qd & 3;
    const int prow = ((((lo == 1) || (lo == 2)) ? (qd ^ 3) : qd) << 2) | (m32 & 3);

    // fused q load + L2-normalize for both q-groups; scale folded with LOG2E
    bf16x8 aqA[4], aqB[4];
    {
        long base = (long)(b * 2048 + q0 + m32) * 3072 + h * 64;
        float e[32]; float ss = 0.f;
        for (int f = 0; f < 4; ++f) {
            aqA[f] = *(const bf16x8*)&qkv[base + f * 16 + half * 8];
            for (int j = 0; j < 8; ++j) { float x = bf2f((unsigned short)aqA[f][j]); e[f * 8 + j] = x; ss += x * x; }
        }
        ss += __shfl_xor(ss, 32, 64);
        float rs = (scale * LOG2E) / fmaxf(sqrtf(ss), 1e-12f);
        for (int f = 0; f < 4; ++f)
            for (int j = 0; j < 8; ++j) aqA[f][j] = (short)f2bf(e[f * 8 + j] * rs);
    }
    {
        long base = (long)(b * 2048 + q0 + 32 + m32) * 3072 + h * 64;
        float e[32]; float ss = 0.f;
        for (int f = 0; f < 4; ++f) {
            aqB[f] = *(const bf16x8*)&qkv[base + f * 16 + half * 8];
            for (int j = 0; j < 8; ++j) { float x = bf2f((unsigned short)aqB[f][j]); e[f * 8 + j] = x; ss += x * x; }
        }
        ss += __shfl_xor(ss, 32, 64);
        float rs = (scale * LOG2E) / fmaxf(sqrtf(ss), 1e-12f);
        for (int f = 0; f < 4; ++f)
            for (int j = 0; j < 8; ++j) aqB[f][j] = (short)f2bf(e[f * 8 + j] * rs);
    }

    f32x16 oA0 = {}, oA1 = {}, lA = {};
    f32x16 oB0 = {}, oB1 = {}, lB = {};
    bf16x8 ones; for (int i = 0; i < 8; ++i) ones[i] = (short)0x3F80;
    const int sr = t >> 2, sc = (t & 3) * 16;
    // K rows live in the qkv k-plane: row l at qkv[(b*2048+l)*3072 + 1024 + h*64]
    const long kqrow = (long)(b * 2048) * 3072 + 1024 + h * 64;
    const long vbase = (long)bh * 64 * 2048;

#define LOADT(kt) \
    kpA = *(const bf16x8*)&qkv[kqrow + (long)((kt) + sr) * 3072 + sc];      \
    kpB = *(const bf16x8*)&qkv[kqrow + (long)((kt) + sr) * 3072 + sc + 8];  \
    vpA = *(const bf16x8*)&vT[vbase + (long)sr * 2048 + (kt) + sc];         \
    vpB = *(const bf16x8*)&vT[vbase + (long)sr * 2048 + (kt) + sc + 8];

#define STORET(buf) \
    *(bf16x8*)&Ks[buf][sr * 72 + sc]     = kpA;  \
    *(bf16x8*)&Ks[buf][sr * 72 + sc + 8] = kpB;  \
    *(bf16x8*)&Vs[buf][sr * 72 + sc]     = vpA;  \
    *(bf16x8*)&Vs[buf][sr * 72 + sc + 8] = vpB;

// QK^T + exp2 + pack for one q-group (AQ) into two packed A-frags (AP0,AP1)
#define SCORE(AQ, AP0, AP1, KF0, KF1, KF2, KF3, SUB) \
    {                                                                                      \
        f32x16 s = {};                                                                     \
        s = __builtin_amdgcn_mfma_f32_32x32x16_bf16(KF0, AQ[0], s, 0, 0, 0);               \
        s = __builtin_amdgcn_mfma_f32_32x32x16_bf16(KF1, AQ[1], s, 0, 0, 0);               \
        s = __builtin_amdgcn_mfma_f32_32x32x16_bf16(KF2, AQ[2], s, 0, 0, 0);               \
        s = __builtin_amdgcn_mfma_f32_32x32x16_bf16(KF3, AQ[3], s, 0, 0, 0);               \
        unsigned pu[16];                                                                   \
        for (int j = 0; j < 16; ++j)                                                       \
            pu[j] = fbits(__builtin_amdgcn_exp2f(s[j] - (SUB)));                           \
        uint4 a0u, a1u;                                                                    \
        a0u.x = __builtin_amdgcn_perm(pu[1],  pu[0],  0x07060302u);                        \
        a0u.y = __builtin_amdgcn_perm(pu[3],  pu[2],  0x07060302u);                        \
        a0u.z = __builtin_amdgcn_perm(pu[5],  pu[4],  0x07060302u);                        \
        a0u.w = __builtin_amdgcn_perm(pu[7],  pu[6],  0x07060302u);                        \
        a1u.x = __builtin_amdgcn_perm(pu[9],  pu[8],  0x07060302u);                        \
        a1u.y = __builtin_amdgcn_perm(pu[11], pu[10], 0x07060302u);                        \
        a1u.z = __builtin_amdgcn_perm(pu[13], pu[12], 0x07060302u);                        \
        a1u.w = __builtin_amdgcn_perm(pu[15], pu[14], 0x07060302u);                        \
        __builtin_memcpy(&AP0, &a0u, 16); __builtin_memcpy(&AP1, &a1u, 16);                \
    }

#define ATTN_STEP(KS, VS, SUB) \
    for (int ktile = 0; ktile < 2; ++ktile) {                                              \
        const unsigned short* krow = &KS[(ktile * 32 + prow) * 72 + half * 8];             \
        bf16x8 kf0 = *(const bf16x8*)&krow[0];                                             \
        bf16x8 kf1 = *(const bf16x8*)&krow[16];                                            \
        bf16x8 kf2 = *(const bf16x8*)&krow[32];                                            \
        bf16x8 kf3 = *(const bf16x8*)&krow[48];                                            \
        bf16x8 apA0, apA1, apB0, apB1;                                                     \
        SCORE(aqA, apA0, apA1, kf0, kf1, kf2, kf3, SUB)                                    \
        SCORE(aqB, apB0, apB1, kf0, kf1, kf2, kf3, SUB)                                    \
        for (int c = 0; c < 2; ++c) {                                                      \
            bf16x8 aA = c ? apA1 : apA0;                                                   \
            bf16x8 aB = c ? apB1 : apB0;                                                   \
            bf16x8 bv0 = *(const bf16x8*)&VS[m32 * 72        + ktile * 32 + c * 16 + half * 8]; \
            bf16x8 bv1 = *(const bf16x8*)&VS[(32 + m32) * 72 + ktile * 32 + c * 16 + half * 8]; \
            oA0 = __builtin_amdgcn_mfma_f32_32x32x16_bf16(aA, bv0, oA0, 0, 0, 0);          \
            oA1 = __builtin_amdgcn_mfma_f32_32x32x16_bf16(aA, bv1, oA1, 0, 0, 0);          \
            lA  = __builtin_amdgcn_mfma_f32_32x32x16_bf16(aA, ones, lA, 0, 0, 0);          \
            oB0 = __builtin_amdgcn_mfma_f32_32x32x16_bf16(aB, bv0, oB0, 0, 0, 0);          \
            oB1 = __builtin_amdgcn_mfma_f32_32x32x16_bf16(aB, bv1, oB1, 0, 0, 0);          \
            lB  = __builtin_amdgcn_mfma_f32_32x32x16_bf16(aB, ones, lB, 0, 0, 0);          \
        }                                                                                  \
    }

#define KLOOP(SUB) \
    for (int kt = 0; kt < 2048; kt += 128) {                 \
        LOADT(kt + 64)                                       \
        ATTN_STEP(Ks[0], Vs[0], SUB)                         \
        STORET(1)                                            \
        __syncthreads();                                     \
        const bool more = (kt + 128) < 2048;                 \
        if (more) { LOADT(kt + 128) }                        \
        ATTN_STEP(Ks[1], Vs[1], SUB)                         \
        if (more) {                                          \
            STORET(0)                                        \
            __syncthreads();                                 \
        }                                                    \
    }

    bf16x8 kpA, kpB, vpA, vpB;
    LOADT(0)
    STORET(0)
    __syncthreads();

    if (c2 < 30.0f) {      // wave-uniform; scale=4 here => fast path
        KLOOP(0.0f)        // s - 0.0f folds away: no per-score VALU shift
    } else {
        KLOOP(c2)          // overflow-safe general path
    }
#undef LOADT
#undef STORET
#undef SCORE
#undef ATTN_STEP
#undef KLOOP

    // epilogue: divide by rowsum (lacc reg r matches o reg r), write attn[B,L,C]
    for (int r = 0; r < 16; ++r) {
        int m = (r & 3) + 8 * (r >> 2) + 4 * half;
        float invA = 1.0f / lA[r];
        long dstA = (long)(b * 2048 + q0 + m) * 1024 + h * 64;
        attn[dstA + m32]      = f2bf(oA0[r] * invA);
        attn[dstA + 32 + m32] = f2bf(oA1[r] * invA);
        float invB = 1.0f / lB[r];
        long dstB = (long)(b * 2048 + q0 + 32 + m) * 1024 + h * 64;
        attn[dstB + m32]      = f2bf(oB0[r] * invB);
        attn[dstB + 32 + m32] = f2bf(oB1[r] * invB);
    }
}

// ---------------------------------------------------------------------------
extern "C" void kernel_launch(void* const* d_in, const int* in_sizes, int n_in,
                              void* d_out, int out_size, void* d_ws, size_t ws_size,
                              hipStream_t stream) {
    const float* x    = (const float*)d_in[0];
    const float* Wqkv = (const float*)d_in[1];
    const float* qbia = (const float*)d_in[2];
    const float* vbia = (const float*)d_in[3];
    const float* sml  = (const float*)d_in[4];
    const float* Wp   = (const float*)d_in[5];
    const float* bp   = (const float*)d_in[6];

    char* ws = (char*)d_ws;
    unsigned short* qkv   = (unsigned short*)ws;                    // [0, 50.33MB)
    unsigned short* Wqkvb = (unsigned short*)(ws + 50331648);       // 6.29MB
    unsigned short* vT    = (unsigned short*)(ws + 67108864);       // hosts xb first
    unsigned short* xb    = vT;
    unsigned short* attnb = (unsigned short*)(ws + 83886080);
    float*          bias3 = (float*)(ws + 100663296);               // 12KB
    unsigned short* Wpb   = (unsigned short*)(ws + 100679680);      // 2MB
    float*          out   = (float*)d_out;

    hipLaunchKernelGGL(k_prep, dim3(6146), dim3(256), 0, stream,
                       x, Wqkv, Wp, qbia, vbia, xb, Wqkvb, Wpb, bias3);
    hipLaunchKernelGGL((k_gemm_lds<false, true, true, true>), dim3(64, 24), dim3(256), 0, stream,
                       xb, Wqkvb, bias3, (void*)qkv, 3072, 1024);
    hipLaunchKernelGGL(k_prep_v, dim3(32, 64), dim3(256), 0, stream, qkv, vT);
    hipLaunchKernelGGL(k_attn32, dim3(512), dim3(256), 0, stream, qkv, vT, sml, attnb);
    hipLaunchKernelGGL((k_gemm_lds<true, false, false, true>), dim3(64, 8), dim3(256), 0, stream,
                       attnb, Wpb, bp, (void*)out, 1024, 1024);
}